// Round 1
// baseline (455.617 us; speedup 1.0000x reference)
//
#include <hip/hip_runtime.h>
#include <hip/hip_bf16.h>

// HardLabel: per pixel (n,h,w):
//   gt = first c with label[n,c,h,w] > 0
//   cond = has_label && (prob[n,gt,h,w] < 0.9 || rand[n,h,w] < 0.9)
//   out[n,c,h,w] = (c == gt && cond) ? 1.0f : 0.0f
//
// Memory-bound. Key trick: prob is only read when rand >= 0.9 (~10% of
// pixels), as a per-lane predicated scalar gather. label read + out write
// (216 MB each) dominate.

#define THR 0.9f
#define N_ 8
#define C_ 22
#define H_ 480
#define W_ 640
#define HW_ (H_ * W_)          // 307200
#define PIX_ (N_ * HW_)        // 2457600

__global__ __launch_bounds__(256) void hardlabel_kernel(
    const float* __restrict__ prob,
    const float* __restrict__ label,
    const float* __restrict__ rnd,
    float* __restrict__ out) {

    int t = blockIdx.x * blockDim.x + threadIdx.x;  // one thread per 4 pixels
    int p = t * 4;                                  // flat pixel index over N*H*W
    if (p >= PIX_) return;

    int n  = p / HW_;            // image index (float4 never crosses n: HW%4==0)
    int pw = p - n * HW_;        // flat pixel offset within image

    const size_t img_off = (size_t)n * C_ * HW_ + pw;
    const float* labn  = label + img_off;
    const float* probn = prob  + img_off;
    float*       outn  = out   + img_off;

    // ---- scan label channels: first c with label > 0 per pixel ----
    int gt0 = -1, gt1 = -1, gt2 = -1, gt3 = -1;
    #pragma unroll
    for (int c = 0; c < C_; ++c) {
        float4 lv = *(const float4*)(labn + (size_t)c * HW_);
        gt0 = (gt0 < 0 && lv.x > 0.0f) ? c : gt0;
        gt1 = (gt1 < 0 && lv.y > 0.0f) ? c : gt1;
        gt2 = (gt2 < 0 && lv.z > 0.0f) ? c : gt2;
        gt3 = (gt3 < 0 && lv.w > 0.0f) ? c : gt3;
    }

    // ---- rand draw ----
    float4 rv = *(const float4*)(rnd + p);

    // ---- cond per pixel; prob gather only when rand >= THR ----
    float c0, c1, c2, c3;
    {
        if (gt0 < 0)            c0 = 0.0f;
        else if (rv.x < THR)    c0 = 1.0f;
        else                    c0 = (probn[(size_t)gt0 * HW_ + 0] < THR) ? 1.0f : 0.0f;

        if (gt1 < 0)            c1 = 0.0f;
        else if (rv.y < THR)    c1 = 1.0f;
        else                    c1 = (probn[(size_t)gt1 * HW_ + 1] < THR) ? 1.0f : 0.0f;

        if (gt2 < 0)            c2 = 0.0f;
        else if (rv.z < THR)    c2 = 1.0f;
        else                    c2 = (probn[(size_t)gt2 * HW_ + 2] < THR) ? 1.0f : 0.0f;

        if (gt3 < 0)            c3 = 0.0f;
        else if (rv.w < THR)    c3 = 1.0f;
        else                    c3 = (probn[(size_t)gt3 * HW_ + 3] < THR) ? 1.0f : 0.0f;
    }

    // ---- write one-hot * cond across all channels ----
    #pragma unroll
    for (int c = 0; c < C_; ++c) {
        float4 o;
        o.x = (gt0 == c) ? c0 : 0.0f;
        o.y = (gt1 == c) ? c1 : 0.0f;
        o.z = (gt2 == c) ? c2 : 0.0f;
        o.w = (gt3 == c) ? c3 : 0.0f;
        *(float4*)(outn + (size_t)c * HW_) = o;
    }
}

extern "C" void kernel_launch(void* const* d_in, const int* in_sizes, int n_in,
                              void* d_out, int out_size, void* d_ws, size_t ws_size,
                              hipStream_t stream) {
    const float* prob  = (const float*)d_in[0];
    const float* label = (const float*)d_in[1];
    const float* rnd   = (const float*)d_in[2];
    float* out = (float*)d_out;

    const int threads = PIX_ / 4;            // 614400
    const int block = 256;
    const int grid = (threads + block - 1) / block;  // 2400
    hardlabel_kernel<<<grid, block, 0, stream>>>(prob, label, rnd, out);
}

// Round 3
// 451.553 us; speedup vs baseline: 1.0090x; 1.0090x over previous
//
#include <hip/hip_runtime.h>
#include <hip/hip_bf16.h>

// HardLabel: per pixel (n,h,w):
//   gt = first c with label[n,c,h,w] > 0
//   cond = has_label && (prob[n,gt,h,w] < 0.9 || rand[n,h,w] < 0.9)
//   out[n,c,h,w] = (c == gt && cond) ? 1.0f : 0.0f
//
// Memory-bound streaming kernel, zero reuse:
//   label 216 MB R + out 216 MB W + rand 10 MB R + sparse prob ~15 MB R
//   floor ~457 MB / 6.3 TB/s ~ 73 us.
// Round 3: nontemporal hints via native ext_vector_type float4 (HIP's
// float4 class is rejected by the builtin). rand load hoisted above the
// label scan for latency overlap. prob stays a predicated per-lane gather:
// only ~10% of pixels (rand >= thr) need it (216 MB -> ~15 MB).

#define THR 0.9f
#define N_ 8
#define C_ 22
#define H_ 480
#define W_ 640
#define HW_ (H_ * W_)          // 307200
#define PIX_ (N_ * HW_)        // 2457600

typedef float vf4 __attribute__((ext_vector_type(4)));

__global__ __launch_bounds__(256) void hardlabel_kernel(
    const float* __restrict__ prob,
    const float* __restrict__ label,
    const float* __restrict__ rnd,
    float* __restrict__ out) {

    int t = blockIdx.x * blockDim.x + threadIdx.x;  // one thread per 4 pixels
    int p = t * 4;                                  // flat pixel index over N*H*W
    if (p >= PIX_) return;

    int n  = p / HW_;            // image index (float4 never crosses n: HW%4==0)
    int pw = p - n * HW_;        // flat pixel offset within image

    const size_t img_off = (size_t)n * C_ * HW_ + pw;
    const float* labn  = label + img_off;
    const float* probn = prob  + img_off;
    float*       outn  = out   + img_off;

    // ---- rand draw first: overlap its latency with the label scan ----
    vf4 rv = __builtin_nontemporal_load((const vf4*)(rnd + p));

    // ---- scan label channels: first c with label > 0 per pixel ----
    int gt0 = -1, gt1 = -1, gt2 = -1, gt3 = -1;
    #pragma unroll
    for (int c = 0; c < C_; ++c) {
        vf4 lv = __builtin_nontemporal_load((const vf4*)(labn + (size_t)c * HW_));
        gt0 = (gt0 < 0 && lv.x > 0.0f) ? c : gt0;
        gt1 = (gt1 < 0 && lv.y > 0.0f) ? c : gt1;
        gt2 = (gt2 < 0 && lv.z > 0.0f) ? c : gt2;
        gt3 = (gt3 < 0 && lv.w > 0.0f) ? c : gt3;
    }

    // ---- cond per pixel; prob gather only when rand >= THR (~10%) ----
    float c0, c1, c2, c3;
    {
        if (gt0 < 0)            c0 = 0.0f;
        else if (rv.x < THR)    c0 = 1.0f;
        else                    c0 = (probn[(size_t)gt0 * HW_ + 0] < THR) ? 1.0f : 0.0f;

        if (gt1 < 0)            c1 = 0.0f;
        else if (rv.y < THR)    c1 = 1.0f;
        else                    c1 = (probn[(size_t)gt1 * HW_ + 1] < THR) ? 1.0f : 0.0f;

        if (gt2 < 0)            c2 = 0.0f;
        else if (rv.z < THR)    c2 = 1.0f;
        else                    c2 = (probn[(size_t)gt2 * HW_ + 2] < THR) ? 1.0f : 0.0f;

        if (gt3 < 0)            c3 = 0.0f;
        else if (rv.w < THR)    c3 = 1.0f;
        else                    c3 = (probn[(size_t)gt3 * HW_ + 3] < THR) ? 1.0f : 0.0f;
    }

    // ---- write one-hot * cond across all channels (full-line streaming) ----
    #pragma unroll
    for (int c = 0; c < C_; ++c) {
        vf4 o;
        o.x = (gt0 == c) ? c0 : 0.0f;
        o.y = (gt1 == c) ? c1 : 0.0f;
        o.z = (gt2 == c) ? c2 : 0.0f;
        o.w = (gt3 == c) ? c3 : 0.0f;
        __builtin_nontemporal_store(o, (vf4*)(outn + (size_t)c * HW_));
    }
}

extern "C" void kernel_launch(void* const* d_in, const int* in_sizes, int n_in,
                              void* d_out, int out_size, void* d_ws, size_t ws_size,
                              hipStream_t stream) {
    const float* prob  = (const float*)d_in[0];
    const float* label = (const float*)d_in[1];
    const float* rnd   = (const float*)d_in[2];
    float* out = (float*)d_out;

    const int threads = PIX_ / 4;            // 614400
    const int block = 256;
    const int grid = (threads + block - 1) / block;  // 2400
    hardlabel_kernel<<<grid, block, 0, stream>>>(prob, label, rnd, out);
}